// Round 8
// baseline (202.646 us; speedup 1.0000x reference)
//
#include <hip/hip_runtime.h>

// VQ-VAE VectorQuantizer forward for MI355X (gfx950) — MFMA-filtered argmin.
// z_e: (64, 256, 32, 32) fp32; codebook: (512, 256) fp32.
// Outputs concatenated in d_out (float32):
//   [0, 16777216)        z_q_st  (== z_e + (z_q - z_e), fp32 elementwise)
//   [16777216]           commitment_loss
//   [16777217]           codebook_loss (same value)
//   [16777218, +65536)   indices (as float)
//
// Index semantics: bitwise emulation of numpy-fp32
//   d = sum(z**2,axis=1,keepdims=True) + sum(e**2,axis=1) - 2*matmul(z, e.T)
//   idx = argmin(d, axis=1)   (first occurrence on exact fp32 ties)
// Pipeline:
//   vq_prep    : bf16 codebook + exact pairwise ||e||^2; zero pending counter
//   vq_argmin3 : MFMA approx scores; n==1 rows resolved; n>=2 rows appended
//                to a global pending list (block-aggregated atomic)
//   vq_exact   : wave per pending row; z row staged to LDS; bitwise numpy
//                fp32 chain per candidate; (d asc, k asc) reduce
//   vq_gather2 : streaming gather / straight-through / loss partials
//   vq_finish  : deterministic loss reduction
//
// NOTE on __launch_bounds__: the MFMA accumulator needs 64 regs; caps
// tighter than (256,4) force acc spill to scratch (round-6 rocprof:
// 322 MB of HBM writes = pure spill traffic). Keep (256,4).

typedef __attribute__((ext_vector_type(8))) short short8v;
typedef __attribute__((ext_vector_type(4))) float float4v;
typedef unsigned short ushort_t;

namespace {
constexpr int K = 512;
constexpr int D = 256;
constexpr int HW = 1024;          // 32*32
constexpr int NROWS = 65536;      // 64*HW
constexpr int CHW = D * HW;       // 262144

constexpr int ZQ_SIZE = 64 * CHW; // 16777216
constexpr int LOSS0_OFF = ZQ_SIZE;
constexpr int LOSS1_OFF = ZQ_SIZE + 1;
constexpr int IDX_OFF = ZQ_SIZE + 2;

// workspace layout (float offsets); total ~2.1 MB
constexpr int WS_EH_FLOATS = (K * D) / 2;   // eH bf16[512][256] (256 KB)
constexpr int WS_B = WS_EH_FLOATS;          // ||e_k||^2, 512
constexpr int WS_A = WS_B + K;              // ||z_row||^2 per row, 65536
constexpr int WS_KIDX = WS_A + NROWS;       // best index per row (int), 65536
constexpr int WS_PART = WS_KIDX + NROWS;    // loss partials, 2048
constexpr int WS_PCNT = WS_PART + 2048;     // pending counter (int), +4
constexpr int WS_PMETA = WS_PCNT + 4;       // pending row|n<<16 (u32), 65536
constexpr int WS_PCAND = WS_PMETA + NROWS;  // pending cands (u16 x8), 131072 fl

constexpr int NBLK_A = NROWS / 32;          // 2048 argmin blocks (32 rows)
constexpr int NBLK_G = 2048;                // gather blocks
constexpr int NBLK_E = 1024;                // exact blocks (4 waves each)

constexpr float EPS_CAND = 3.0e-3f;         // candidate window (>> 2*max err)
constexpr int MAXC = 8;                     // stored candidates; n>8 full-scans
}  // namespace

__device__ __forceinline__ ushort_t bf16_rne(float f) {
    unsigned u = __float_as_uint(f);
    u += 0x7fffu + ((u >> 16) & 1u);   // round-to-nearest-even (no NaN in data)
    return (ushort_t)(u >> 16);
}

// ---------------------------------------------------------------------------
// Kernel 1: eH[k][d] = bf16(cb[k][d]); B[k] = ||e_k||^2 in numpy pairwise
// order; block 0 zeroes the pending counter for this launch.
__global__ void vq_prep(const float* __restrict__ cb, float* __restrict__ ws) {
    const int k = blockIdx.x;
    const int t = threadIdx.x;  // 0..255 == d
    if (k == 0 && t == 0) reinterpret_cast<int*>(ws + WS_PCNT)[0] = 0;
    ushort_t* eh = (ushort_t*)ws;
    eh[(size_t)k * D + t] = bf16_rne(cb[k * D + t]);
    __shared__ float r16[16];
    if (t < 16) {
#pragma clang fp contract(off)
        const float* x = cb + k * D + (t >> 3) * 128;
        const int j = t & 7;
        float v = x[j];
        float r = v * v;
        for (int i = 1; i < 16; ++i) {
            float w = x[8 * i + j];
            r += w * w;
        }
        r16[t] = r;
    }
    __syncthreads();
    if (t == 0) {
#pragma clang fp contract(off)
        float lo = ((r16[0] + r16[1]) + (r16[2] + r16[3])) +
                   ((r16[4] + r16[5]) + (r16[6] + r16[7]));
        float hi = ((r16[8] + r16[9]) + (r16[10] + r16[11])) +
                   ((r16[12] + r16[13]) + (r16[14] + r16[15]));
        ws[WS_B + k] = lo + hi;
    }
}

// ---------------------------------------------------------------------------
// Kernel 2: argmin filter. Per 32-row block (~22 KB LDS):
//   fused single z pass: numpy-pairwise A chains + bf16-hi -> LDS;
//   MFMA approx scores; per-row min; candidate collection (<= min+EPS);
//   n==1 rows resolved here; n>=2 rows appended to global pending list.
__global__ __launch_bounds__(256, 4) void vq_argmin3(
    const float* __restrict__ z_e, const ushort_t* __restrict__ eh,
    const float* __restrict__ Bv, float* __restrict__ wsA,
    int* __restrict__ gpcnt, unsigned* __restrict__ pmeta,
    ushort_t* __restrict__ pcand, int* __restrict__ wsidx,
    float* __restrict__ out) {
    __shared__ __align__(16) ushort_t zh[32][264];    // 16.9 KB bf16 hi, padded
    __shared__ float lds_B[K];                        // 2 KB ||e_k||^2
    __shared__ float scr[32][17];                     // 2.2 KB pairwise accums
    __shared__ int cand[32][MAXC];                    // 1 KB candidate codes
    __shared__ float lds_A[32];
    __shared__ float wmin[4][32];
    __shared__ float rmin[32];
    __shared__ int cnt[32];

    const int t = threadIdx.x;
    const int row0 = blockIdx.x * 32;
    const int b = row0 >> 10;
    const int hw0 = row0 & 1023;
    const float* zbase = z_e + (size_t)b * CHW + hw0;

    // ---- B staging
    lds_B[t] = Bv[t];
    lds_B[t + 256] = Bv[t + 256];

    // ---- fused: A pairwise chains + bf16-hi conversion (single z read).
    {
        const int row = t & 31;
        const int q = t >> 5;
        const int half = q >> 2;
        const int j0 = (q & 3) * 2;
        const int cbase = half * 128;
        const float* zp = zbase + row;
        float r0, r1;
        {
#pragma clang fp contract(off)
            const int c0 = cbase + j0;
            float w0 = zp[(size_t)c0 * HW];
            float w1 = zp[(size_t)(c0 + 1) * HW];
            r0 = w0 * w0;
            r1 = w1 * w1;
            *reinterpret_cast<unsigned*>(&zh[row][c0]) =
                (unsigned)bf16_rne(w0) | ((unsigned)bf16_rne(w1) << 16);
            for (int i = 1; i < 16; ++i) {
                const int c = cbase + 8 * i + j0;
                float u0 = zp[(size_t)c * HW];
                float u1 = zp[(size_t)(c + 1) * HW];
                r0 += u0 * u0;
                r1 += u1 * u1;
                *reinterpret_cast<unsigned*>(&zh[row][c]) =
                    (unsigned)bf16_rne(u0) | ((unsigned)bf16_rne(u1) << 16);
            }
        }
        scr[row][half * 8 + j0] = r0;
        scr[row][half * 8 + j0 + 1] = r1;
    }
    __syncthreads();
    if (t < 32) {
#pragma clang fp contract(off)
        const float* r = scr[t];
        float lo = ((r[0] + r[1]) + (r[2] + r[3])) + ((r[4] + r[5]) + (r[6] + r[7]));
        float hi = ((r[8] + r[9]) + (r[10] + r[11])) + ((r[12] + r[13]) + (r[14] + r[15]));
        lds_A[t] = lo + hi;
        wsA[row0 + t] = lo + hi;
    }

    // ---- MFMA main loop: wave w owns codes [w*128, w*128+128), all 32 rows.
    // A = E (codes = M), B = Z-hi (rows = N). hi term only.
    // C frag (m89-verified): col = lane&15 = z-row; row = 4*(lane>>4)+reg = code.
    const int lane = t & 63;
    const int w = t >> 6;
    const int wc0 = w * 128;
    const int l15 = lane & 15;
    const int kg = lane >> 4;

    float4v acc[8][2];
#pragma unroll
    for (int c = 0; c < 8; ++c)
#pragma unroll
        for (int rt = 0; rt < 2; ++rt) acc[c][rt] = (float4v)0.f;

    const ushort_t* ehp = eh + (size_t)(wc0 + l15) * D + 8 * kg;

#pragma unroll 4
    for (int d0 = 0; d0 < D; d0 += 32) {
        const short8v bh0 = *reinterpret_cast<const short8v*>(&zh[l15][d0 + 8 * kg]);
        const short8v bh1 = *reinterpret_cast<const short8v*>(&zh[16 + l15][d0 + 8 * kg]);
#pragma unroll
        for (int c = 0; c < 8; ++c) {
            const short8v a = *reinterpret_cast<const short8v*>(ehp + c * 16 * D + d0);
            acc[c][0] = __builtin_amdgcn_mfma_f32_16x16x32_bf16(a, bh0, acc[c][0], 0, 0, 0);
            acc[c][1] = __builtin_amdgcn_mfma_f32_16x16x32_bf16(a, bh1, acc[c][1], 0, 0, 0);
        }
    }
    __syncthreads();  // lds_A ready for all

    // ---- approx scores + per-row min
    float lmin0 = 3.0e38f, lmin1 = 3.0e38f;
#pragma unroll
    for (int c = 0; c < 8; ++c)
#pragma unroll
        for (int rt = 0; rt < 2; ++rt)
#pragma unroll
            for (int r = 0; r < 4; ++r) {
                const int code = wc0 + 16 * c + 4 * kg + r;
                const int row = rt * 16 + l15;
                float s = (lds_A[row] + lds_B[code]) - 2.0f * acc[c][rt][r];
                acc[c][rt][r] = s;
                if (rt == 0) lmin0 = fminf(lmin0, s);
                else lmin1 = fminf(lmin1, s);
            }
    lmin0 = fminf(lmin0, __shfl_xor(lmin0, 16));
    lmin0 = fminf(lmin0, __shfl_xor(lmin0, 32));
    lmin1 = fminf(lmin1, __shfl_xor(lmin1, 16));
    lmin1 = fminf(lmin1, __shfl_xor(lmin1, 32));
    if (lane < 16) {
        wmin[w][l15] = lmin0;
        wmin[w][16 + l15] = lmin1;
    }
    __syncthreads();
    if (t < 32) {
        rmin[t] = fminf(fminf(wmin[0][t], wmin[1][t]), fminf(wmin[2][t], wmin[3][t]));
        cnt[t] = 0;
    }
    __syncthreads();

    // ---- candidate collection (any possible exact winner is within EPS)
#pragma unroll
    for (int c = 0; c < 8; ++c)
#pragma unroll
        for (int rt = 0; rt < 2; ++rt) {
            const int row = rt * 16 + l15;
            const float thr = rmin[row] + EPS_CAND;
#pragma unroll
            for (int r = 0; r < 4; ++r) {
                if (acc[c][rt][r] <= thr) {
                    const int code = wc0 + 16 * c + 4 * kg + r;
                    int slot = atomicAdd(&cnt[row], 1);
                    if (slot < MAXC) cand[row][slot] = code;
                }
            }
        }
    __syncthreads();

    // ---- resolve n==1 rows; append n>=2 rows to global pending list.
    // One atomicAdd per block (wave-0 ballot + popcount prefix).
    if (t < 64) {
        const int n = (t < 32) ? cnt[t] : 0;
        const bool pend = (t < 32) && (n >= 2);
        const unsigned long long m = __ballot(pend);
        int base = 0;
        if (t == 0 && m != 0ull) base = atomicAdd(gpcnt, __popcll(m));
        base = __shfl(base, 0);
        if (t < 32) {
            if (n == 1) {
                const int bk = cand[t][0];
                wsidx[row0 + t] = bk;
                out[IDX_OFF + row0 + t] = (float)bk;
            } else {
                const int slot = base + __popcll(m & ((1ull << t) - 1ull));
                pmeta[slot] = (unsigned)(row0 + t) | ((unsigned)n << 16);
                const int ns = (n < MAXC) ? n : MAXC;
                for (int j = 0; j < ns; ++j)
                    pcand[(size_t)slot * MAXC + j] = (ushort_t)cand[t][j];
            }
        }
    }
}

// ---------------------------------------------------------------------------
// Kernel 3: exact re-score of pending rows. One wave per row, grid-strided.
// Wave stages the row's 256 z floats into LDS (one latency exposure), then
// lane l runs candidate l's bitwise numpy fp32 chain from LDS (ascending d,
// sequential fmaf). Reduce (d asc, tie k asc) == numpy first occurrence.
// n > MAXC (P ~ 1e-10): full scan of all 512 codes, 8 chains/lane.
__global__ __launch_bounds__(256) void vq_exact(
    const float* __restrict__ z_e, const float* __restrict__ cb,
    const float* __restrict__ Bv, const float* __restrict__ wsA,
    const unsigned* __restrict__ pmeta, const ushort_t* __restrict__ pcand,
    const int* __restrict__ gpcnt, int* __restrict__ wsidx,
    float* __restrict__ out) {
    __shared__ float zx[4][260];
    const int t = threadIdx.x;
    const int wv = t >> 6;
    const int lane = t & 63;
    const int nw = gridDim.x * 4;
    const int total = *gpcnt;

    for (int slot = blockIdx.x * 4 + wv; slot < total; slot += nw) {
        const unsigned mt = pmeta[slot];
        const int r = mt & 0xFFFFu;
        const int n = (int)(mt >> 16);
        const int b = r >> 10;
        const int hw = r & 1023;
        const float* zp = z_e + (size_t)b * CHW + hw;
#pragma unroll
        for (int i = 0; i < 4; ++i)
            zx[wv][lane + 64 * i] = zp[(size_t)(lane + 64 * i) * HW];
        const float aval = wsA[r];
        float bd = 3.0e38f;
        int bk = 0x7fffffff;
        if (n <= MAXC) {
            if (lane < n) {
                const int k = pcand[(size_t)slot * MAXC + lane];
                const float* ep = cb + (size_t)k * D;
                float a = 0.f;
#pragma unroll 8
                for (int c = 0; c < D; ++c) a = fmaf(zx[wv][c], ep[c], a);
                {
#pragma clang fp contract(off)
                    float t1 = aval + Bv[k];
                    bd = t1 - 2.0f * a;
                }
                bk = k;
            }
        } else {
            for (int k = lane; k < K; k += 64) {
                const float* ep = cb + (size_t)k * D;
                float a = 0.f;
#pragma unroll 8
                for (int c = 0; c < D; ++c) a = fmaf(zx[wv][c], ep[c], a);
                float dv;
                {
#pragma clang fp contract(off)
                    float t1 = aval + Bv[k];
                    dv = t1 - 2.0f * a;
                }
                if (dv < bd || (dv == bd && k < bk)) {
                    bd = dv;
                    bk = k;
                }
            }
        }
#pragma unroll
        for (int m = 1; m < 64; m <<= 1) {
            float od = __shfl_xor(bd, m);
            int ok = __shfl_xor(bk, m);
            if (od < bd || (od == bd && ok < bk)) {
                bd = od;
                bk = ok;
            }
        }
        if (lane == 0) {
            wsidx[r] = bk;
            out[IDX_OFF + r] = (float)bk;
        }
    }
}

// ---------------------------------------------------------------------------
// Kernel 4: streaming gather / straight-through write / loss partials.
__global__ __launch_bounds__(256, 8) void vq_gather2(
    const float* __restrict__ z_e, const float* __restrict__ cb,
    const int* __restrict__ wsidx, float* __restrict__ part,
    float* __restrict__ out) {
    __shared__ float wpart[4];
    const int t = threadIdx.x;
    const int blk = blockIdx.x;
    const int cg = blk & 7;        // channel group (32 c)
    const int q = (blk >> 3) & 3;  // hw quarter (256 hw)
    const int b = blk >> 5;        // image
    const int lane = t & 63;
    const int csub = t >> 6;       // 0..3 (wave id)
    const int hw = q * 256 + lane * 4;

    const int4 kk = *reinterpret_cast<const int4*>(&wsidx[b * HW + hw]);
    const float* e0 = cb + (size_t)kk.x * D;
    const float* e1 = cb + (size_t)kk.y * D;
    const float* e2 = cb + (size_t)kk.z * D;
    const float* e3 = cb + (size_t)kk.w * D;
    const size_t zoff = (size_t)b * CHW + hw;

    float accum = 0.f;
#pragma unroll 2
    for (int i = 0; i < 8; ++i) {
        const int c = cg * 32 + csub * 8 + i;
        const size_t off = zoff + (size_t)c * HW;
        const float4 z4 = *reinterpret_cast<const float4*>(&z_e[off]);
        const float ex = e0[c], ey = e1[c], ez = e2[c], ew = e3[c];
        float4 o4;
        o4.x = z4.x + (ex - z4.x);
        o4.y = z4.y + (ey - z4.y);
        o4.z = z4.z + (ez - z4.z);
        o4.w = z4.w + (ew - z4.w);
        *reinterpret_cast<float4*>(&out[off]) = o4;
        accum = fmaf(z4.x - ex, z4.x - ex, accum);
        accum = fmaf(z4.y - ey, z4.y - ey, accum);
        accum = fmaf(z4.z - ez, z4.z - ez, accum);
        accum = fmaf(z4.w - ew, z4.w - ew, accum);
    }
#pragma unroll
    for (int m = 1; m < 64; m <<= 1) accum += __shfl_xor(accum, m);
    if (lane == 0) wpart[csub] = accum;
    __syncthreads();
    if (t == 0) part[blk] = (wpart[0] + wpart[1]) + (wpart[2] + wpart[3]);
}

// ---------------------------------------------------------------------------
// Kernel 5: final loss reduction (2048 partials, fp64, deterministic).
__global__ void vq_finish(const float* __restrict__ part, float* __restrict__ out) {
    const int t = threadIdx.x;  // 256 threads
    double s = 0.0;
#pragma unroll
    for (int i = 0; i < 8; ++i) s += (double)part[t + 256 * i];
#pragma unroll
    for (int m = 1; m < 64; m <<= 1) s += __shfl_xor(s, m);
    __shared__ double wsum[4];
    if ((t & 63) == 0) wsum[t >> 6] = s;
    __syncthreads();
    if (t == 0) {
        double mean = (wsum[0] + wsum[1] + wsum[2] + wsum[3]) / (double)ZQ_SIZE;
        out[LOSS0_OFF] = (float)mean;
        out[LOSS1_OFF] = (float)mean;
    }
}

// ---------------------------------------------------------------------------
extern "C" void kernel_launch(void* const* d_in, const int* in_sizes, int n_in,
                              void* d_out, int out_size, void* d_ws, size_t ws_size,
                              hipStream_t stream) {
    const float* z_e = (const float*)d_in[0];
    const float* cb = (const float*)d_in[1];
    float* out = (float*)d_out;
    float* ws = (float*)d_ws;

    const ushort_t* eh = (const ushort_t*)ws;
    float* Bv = ws + WS_B;
    float* wsA = ws + WS_A;
    int* wsidx = (int*)(ws + WS_KIDX);
    float* part = ws + WS_PART;
    int* gpcnt = (int*)(ws + WS_PCNT);
    unsigned* pmeta = (unsigned*)(ws + WS_PMETA);
    ushort_t* pcand = (ushort_t*)(ws + WS_PCAND);

    vq_prep<<<K, D, 0, stream>>>(cb, ws);
    vq_argmin3<<<NBLK_A, 256, 0, stream>>>(z_e, eh, Bv, wsA, gpcnt, pmeta,
                                           pcand, wsidx, out);
    vq_exact<<<NBLK_E, 256, 0, stream>>>(z_e, cb, Bv, wsA, pmeta, pcand,
                                         gpcnt, wsidx, out);
    vq_gather2<<<NBLK_G, 256, 0, stream>>>(z_e, cb, wsidx, part, out);
    vq_finish<<<1, 256, 0, stream>>>(part, out);
}

// Round 9
// 160.669 us; speedup vs baseline: 1.2613x; 1.2613x over previous
//
#include <hip/hip_runtime.h>

// VQ-VAE VectorQuantizer forward for MI355X (gfx950) — MFMA-filtered argmin.
// z_e: (64, 256, 32, 32) fp32; codebook: (512, 256) fp32.
// Outputs concatenated in d_out (float32):
//   [0, 16777216)        z_q_st  (== z_e + (z_q - z_e), fp32 elementwise)
//   [16777216]           commitment_loss
//   [16777217]           codebook_loss (same value)
//   [16777218, +65536)   indices (as float)
//
// Index semantics: bitwise emulation of numpy-fp32
//   d = sum(z**2,axis=1,keepdims=True) + sum(e**2,axis=1) - 2*matmul(z, e.T)
//   idx = argmin(d, axis=1)   (first occurrence on exact fp32 ties)
// Strategy: bf16(hi)-only MFMA computes approximate scores (|err| << EPS/2);
// per-row candidates within EPS of the approx min are re-scored with the
// bitwise-exact sequential fp32 FMA chain (ascending d) and reduced with
// (d asc, tie -> lower k). Overflowing rows fall back to exact scan of all K.
//
// REGISTER NOTE (round-8 post-mortem): with __launch_bounds__(256,4) the
// compiler allocated only 52 VGPRs -> zero loads in flight -> every eh/z
// load serialized at full L2/HBM latency (MfmaUtil 6%, all pipes idle,
// ~110 us floor). This version uses (256,2) + explicit 2-buffer prefetch
// of the MFMA A-operand and hoisted z loads to restore memory-level
// parallelism. Occupancy drops to 2 blocks/CU by design.

typedef __attribute__((ext_vector_type(8))) short short8v;
typedef __attribute__((ext_vector_type(4))) float float4v;
typedef unsigned short ushort_t;

namespace {
constexpr int K = 512;
constexpr int D = 256;
constexpr int HW = 1024;          // 32*32
constexpr int NROWS = 65536;      // 64*HW
constexpr int CHW = D * HW;       // 262144

constexpr int ZQ_SIZE = 64 * CHW; // 16777216
constexpr int LOSS0_OFF = ZQ_SIZE;
constexpr int LOSS1_OFF = ZQ_SIZE + 1;
constexpr int IDX_OFF = ZQ_SIZE + 2;

// workspace layout (float offsets)
constexpr int WS_EH_FLOATS = (K * D) / 2;  // eH bf16[512][256] = 65536 floats
constexpr int WS_B = WS_EH_FLOATS;         // ||e_k||^2 (numpy pairwise), 512
constexpr int WS_KIDX = WS_B + K;          // best index per row (int), 65536
constexpr int WS_PART = WS_KIDX + NROWS;   // per-block loss partials, 2048

constexpr int NBLK_A = NROWS / 32;         // 2048 argmin blocks (32 rows)
constexpr int NBLK_G = 2048;               // 64 img x 4 hw-quarter x 8 c-group

constexpr float EPS_CAND = 3.0e-3f;        // candidate window (>> 2*max err)
constexpr int MAXC = 16;                   // candidate slots per row
}  // namespace

__device__ __forceinline__ ushort_t bf16_rne(float f) {
    unsigned u = __float_as_uint(f);
    u += 0x7fffu + ((u >> 16) & 1u);   // round-to-nearest-even (no NaN in data)
    return (ushort_t)(u >> 16);
}

// ---------------------------------------------------------------------------
// Kernel 1: eH[k][d] = bf16(cb[k][d]); B[k] = ||e_k||^2 in numpy pairwise
// order: pw(x,256)=pw(x,128)+pw(x+128,128); pw(x,128): 8 accums x 16 strided
// adds, then ((r0+r1)+(r2+r3))+((r4+r5)+(r6+r7)).
__global__ void vq_prep(const float* __restrict__ cb, float* __restrict__ ws) {
    const int k = blockIdx.x;
    const int t = threadIdx.x;  // 0..255 == d
    ushort_t* eh = (ushort_t*)ws;
    eh[(size_t)k * D + t] = bf16_rne(cb[k * D + t]);
    __shared__ float r16[16];
    if (t < 16) {
#pragma clang fp contract(off)
        const float* x = cb + k * D + (t >> 3) * 128;
        const int j = t & 7;
        float v = x[j];
        float r = v * v;
        for (int i = 1; i < 16; ++i) {
            float w = x[8 * i + j];
            r += w * w;
        }
        r16[t] = r;
    }
    __syncthreads();
    if (t == 0) {
#pragma clang fp contract(off)
        float lo = ((r16[0] + r16[1]) + (r16[2] + r16[3])) +
                   ((r16[4] + r16[5]) + (r16[6] + r16[7]));
        float hi = ((r16[8] + r16[9]) + (r16[10] + r16[11])) +
                   ((r16[12] + r16[13]) + (r16[14] + r16[15]));
        ws[WS_B + k] = lo + hi;
    }
}

// ---------------------------------------------------------------------------
// Kernel 2: argmin. Per 32-row block (~23 KB LDS, 2 blocks/CU, high ILP):
//   fused single z pass (loads HOISTED to 32 registers) feeding the exact
//   numpy-pairwise A chains + bf16-hi LDS tile;
//   MFMA approx scores with explicit 2-buffer A-operand prefetch;
//   per-row approx min + candidate collection (<= min+EPS);
//   exact fp32-chain re-score of candidates; index write.
__global__ __launch_bounds__(256, 2) void vq_argmin2(
    const float* __restrict__ z_e, const float* __restrict__ cb,
    const ushort_t* __restrict__ eh, const float* __restrict__ Bv,
    int* __restrict__ wsidx, float* __restrict__ out) {
    __shared__ __align__(16) ushort_t zh[32][264];    // 16.9 KB bf16 hi, padded
    __shared__ float lds_B[K];                        // 2 KB ||e_k||^2
    __shared__ float scr[32][17];                     // 2.2 KB pairwise accums
    __shared__ int cand[32][MAXC];                    // 2 KB candidate codes
    __shared__ float lds_A[32];
    __shared__ float wmin[4][32];
    __shared__ float rmin[32];
    __shared__ int cnt[32];

    const int t = threadIdx.x;
    const int row0 = blockIdx.x * 32;
    const int b = row0 >> 10;
    const int hw0 = row0 & 1023;
    const float* zbase = z_e + (size_t)b * CHW + hw0;

    // ---- B staging
    lds_B[t] = Bv[t];
    lds_B[t + 256] = Bv[t + 256];

    // ---- fused: A pairwise chains + bf16-hi conversion (single z read).
    // All 32 loads hoisted into registers first (MLP), then the exact
    // contract(off) chain in numpy order. Values/order bit-identical.
    {
        const int row = t & 31;
        const int q = t >> 5;
        const int half = q >> 2;
        const int j0 = (q & 3) * 2;
        const int cbase = half * 128;
        const float* zp = zbase + row;
        float za0[16], za1[16];
#pragma unroll
        for (int i = 0; i < 16; ++i) {
            const int c = cbase + 8 * i + j0;
            za0[i] = zp[(size_t)c * HW];
            za1[i] = zp[(size_t)(c + 1) * HW];
        }
        float r0, r1;
        {
#pragma clang fp contract(off)
            r0 = za0[0] * za0[0];
            r1 = za1[0] * za1[0];
#pragma unroll
            for (int i = 1; i < 16; ++i) {
                r0 += za0[i] * za0[i];
                r1 += za1[i] * za1[i];
            }
        }
#pragma unroll
        for (int i = 0; i < 16; ++i) {
            const int c = cbase + 8 * i + j0;
            *reinterpret_cast<unsigned*>(&zh[row][c]) =
                (unsigned)bf16_rne(za0[i]) | ((unsigned)bf16_rne(za1[i]) << 16);
        }
        scr[row][half * 8 + j0] = r0;
        scr[row][half * 8 + j0 + 1] = r1;
    }
    __syncthreads();
    if (t < 32) {
#pragma clang fp contract(off)
        const float* r = scr[t];
        float lo = ((r[0] + r[1]) + (r[2] + r[3])) + ((r[4] + r[5]) + (r[6] + r[7]));
        float hi = ((r[8] + r[9]) + (r[10] + r[11])) + ((r[12] + r[13]) + (r[14] + r[15]));
        lds_A[t] = lo + hi;
    }

    // ---- MFMA main loop: wave w owns codes [w*128, w*128+128), all 32 rows.
    // A = E (codes = M), B = Z-hi (rows = N). hi term only.
    // C frag (m89-verified): col = lane&15 = z-row; row = 4*(lane>>4)+reg = code.
    // Explicit 2-buffer prefetch (distance 64 d-units): a0 serves d0 = 0,64,
    // 128,192; a1 serves 32,96,160,224. Prefetch overrun past eh lands in
    // ws[WS_B..] (in-bounds of d_ws, values unused).
    const int lane = t & 63;
    const int w = t >> 6;
    const int wc0 = w * 128;
    const int l15 = lane & 15;
    const int kg = lane >> 4;

    float4v acc[8][2];
#pragma unroll
    for (int c = 0; c < 8; ++c)
#pragma unroll
        for (int rt = 0; rt < 2; ++rt) acc[c][rt] = (float4v)0.f;

    const ushort_t* ehp = eh + (size_t)(wc0 + l15) * D + 8 * kg;

    short8v a0[8], a1[8];
#pragma unroll
    for (int c = 0; c < 8; ++c)
        a0[c] = *reinterpret_cast<const short8v*>(ehp + c * 16 * D + 0);
#pragma unroll
    for (int c = 0; c < 8; ++c)
        a1[c] = *reinterpret_cast<const short8v*>(ehp + c * 16 * D + 32);

#pragma unroll
    for (int d00 = 0; d00 < 256; d00 += 64) {
        {
            const short8v bh0 = *reinterpret_cast<const short8v*>(&zh[l15][d00 + 8 * kg]);
            const short8v bh1 = *reinterpret_cast<const short8v*>(&zh[16 + l15][d00 + 8 * kg]);
#pragma unroll
            for (int c = 0; c < 8; ++c) {
                acc[c][0] = __builtin_amdgcn_mfma_f32_16x16x32_bf16(a0[c], bh0, acc[c][0], 0, 0, 0);
                acc[c][1] = __builtin_amdgcn_mfma_f32_16x16x32_bf16(a0[c], bh1, acc[c][1], 0, 0, 0);
            }
#pragma unroll
            for (int c = 0; c < 8; ++c)
                a0[c] = *reinterpret_cast<const short8v*>(ehp + c * 16 * D + d00 + 64);
        }
        {
            const int d0 = d00 + 32;
            const short8v bh0 = *reinterpret_cast<const short8v*>(&zh[l15][d0 + 8 * kg]);
            const short8v bh1 = *reinterpret_cast<const short8v*>(&zh[16 + l15][d0 + 8 * kg]);
#pragma unroll
            for (int c = 0; c < 8; ++c) {
                acc[c][0] = __builtin_amdgcn_mfma_f32_16x16x32_bf16(a1[c], bh0, acc[c][0], 0, 0, 0);
                acc[c][1] = __builtin_amdgcn_mfma_f32_16x16x32_bf16(a1[c], bh1, acc[c][1], 0, 0, 0);
            }
#pragma unroll
            for (int c = 0; c < 8; ++c)
                a1[c] = *reinterpret_cast<const short8v*>(ehp + c * 16 * D + d0 + 64);
        }
    }
    __syncthreads();  // lds_A ready for all; zh stable until cand phase done

    // ---- approx scores + per-row min
    float lmin0 = 3.0e38f, lmin1 = 3.0e38f;
#pragma unroll
    for (int c = 0; c < 8; ++c)
#pragma unroll
        for (int rt = 0; rt < 2; ++rt)
#pragma unroll
            for (int r = 0; r < 4; ++r) {
                const int code = wc0 + 16 * c + 4 * kg + r;
                const int row = rt * 16 + l15;
                float s = (lds_A[row] + lds_B[code]) - 2.0f * acc[c][rt][r];
                acc[c][rt][r] = s;
                if (rt == 0) lmin0 = fminf(lmin0, s);
                else lmin1 = fminf(lmin1, s);
            }
    lmin0 = fminf(lmin0, __shfl_xor(lmin0, 16));
    lmin0 = fminf(lmin0, __shfl_xor(lmin0, 32));
    lmin1 = fminf(lmin1, __shfl_xor(lmin1, 16));
    lmin1 = fminf(lmin1, __shfl_xor(lmin1, 32));
    if (lane < 16) {
        wmin[w][l15] = lmin0;
        wmin[w][16 + l15] = lmin1;
    }
    __syncthreads();
    if (t < 32) {
        rmin[t] = fminf(fminf(wmin[0][t], wmin[1][t]), fminf(wmin[2][t], wmin[3][t]));
        cnt[t] = 0;
    }
    __syncthreads();

    // ---- candidate collection (any possible exact winner is within EPS)
#pragma unroll
    for (int c = 0; c < 8; ++c)
#pragma unroll
        for (int rt = 0; rt < 2; ++rt) {
            const int row = rt * 16 + l15;
            const float thr = rmin[row] + EPS_CAND;
#pragma unroll
            for (int r = 0; r < 4; ++r) {
                if (acc[c][rt][r] <= thr) {
                    const int code = wc0 + 16 * c + 4 * kg + r;
                    int slot = atomicAdd(&cnt[row], 1);
                    if (slot < MAXC) cand[row][slot] = code;
                }
            }
        }
    __syncthreads();

    // ---- exact pass: bitwise numpy-fp32 chain for rows with >=2 candidates.
    // zh buffer is dead now; alias reduction arrays onto it.
    float* ed = reinterpret_cast<float*>(&zh[0][0]);  // [8][32]
    int* ek = reinterpret_cast<int*>(ed + 256);       // [8][32]
    {
        const int row = t & 31;
        const int ct = t >> 5;  // 0..7 candidate-threads per row
        const float* zp = zbase + row;
        const int n = cnt[row];
        float bd = 3.0e38f;
        int bk = 0x7fffffff;
        if (n == 1) {
            if (ct == 0) {
                bd = -3.0e38f;
                bk = cand[row][0];
            }
        } else {
            const bool full = (n > MAXC);  // overflow: exact-scan all codes
            const int lim = full ? K : n;
            for (int s = ct; s < lim; s += 8) {
                const int k = full ? s : cand[row][s];
                const float* ep = cb + (size_t)k * D;
                float a = 0.f;
#pragma unroll 8
                for (int c = 0; c < D; ++c) a = fmaf(zp[(size_t)c * HW], ep[c], a);
                float dv;
                {
#pragma clang fp contract(off)
                    float t1 = lds_A[row] + lds_B[k];
                    dv = t1 - 2.0f * a;
                }
                if (dv < bd || (dv == bd && k < bk)) {
                    bd = dv;
                    bk = k;
                }
            }
        }
        ed[t] = bd;
        ek[t] = bk;
    }
    __syncthreads();
    if (t < 32) {
        float bd = ed[t];
        int bk = ek[t];
#pragma unroll
        for (int q = 1; q < 8; ++q) {
            float od = ed[q * 32 + t];
            int ok = ek[q * 32 + t];
            if (od < bd || (od == bd && ok < bk)) {
                bd = od;
                bk = ok;
            }
        }
        wsidx[row0 + t] = bk;
        out[IDX_OFF + row0 + t] = (float)bk;
    }
}

// ---------------------------------------------------------------------------
// Kernel 3: streaming gather / straight-through write / loss partials.
// Block: 256 threads = 4 waves; block covers (image b, 256 hw, 32 channels).
__global__ __launch_bounds__(256, 8) void vq_gather2(
    const float* __restrict__ z_e, const float* __restrict__ cb,
    const int* __restrict__ wsidx, float* __restrict__ part,
    float* __restrict__ out) {
    __shared__ float wpart[4];
    const int t = threadIdx.x;
    const int blk = blockIdx.x;
    const int cg = blk & 7;        // channel group (32 c)
    const int q = (blk >> 3) & 3;  // hw quarter (256 hw)
    const int b = blk >> 5;        // image
    const int lane = t & 63;
    const int csub = t >> 6;       // 0..3 (wave id)
    const int hw = q * 256 + lane * 4;

    const int4 kk = *reinterpret_cast<const int4*>(&wsidx[b * HW + hw]);
    const float* e0 = cb + (size_t)kk.x * D;
    const float* e1 = cb + (size_t)kk.y * D;
    const float* e2 = cb + (size_t)kk.z * D;
    const float* e3 = cb + (size_t)kk.w * D;
    const size_t zoff = (size_t)b * CHW + hw;

    float accum = 0.f;
#pragma unroll 2
    for (int i = 0; i < 8; ++i) {
        const int c = cg * 32 + csub * 8 + i;
        const size_t off = zoff + (size_t)c * HW;
        const float4 z4 = *reinterpret_cast<const float4*>(&z_e[off]);
        const float ex = e0[c], ey = e1[c], ez = e2[c], ew = e3[c];
        float4 o4;
        o4.x = z4.x + (ex - z4.x);
        o4.y = z4.y + (ey - z4.y);
        o4.z = z4.z + (ez - z4.z);
        o4.w = z4.w + (ew - z4.w);
        *reinterpret_cast<float4*>(&out[off]) = o4;
        accum = fmaf(z4.x - ex, z4.x - ex, accum);
        accum = fmaf(z4.y - ey, z4.y - ey, accum);
        accum = fmaf(z4.z - ez, z4.z - ez, accum);
        accum = fmaf(z4.w - ew, z4.w - ew, accum);
    }
#pragma unroll
    for (int m = 1; m < 64; m <<= 1) accum += __shfl_xor(accum, m);
    if (lane == 0) wpart[csub] = accum;
    __syncthreads();
    if (t == 0) part[blk] = (wpart[0] + wpart[1]) + (wpart[2] + wpart[3]);
}

// ---------------------------------------------------------------------------
// Kernel 4: final loss reduction (2048 partials, fp64, deterministic).
__global__ void vq_finish(const float* __restrict__ part, float* __restrict__ out) {
    const int t = threadIdx.x;  // 256 threads
    double s = 0.0;
#pragma unroll
    for (int i = 0; i < 8; ++i) s += (double)part[t + 256 * i];
#pragma unroll
    for (int m = 1; m < 64; m <<= 1) s += __shfl_xor(s, m);
    __shared__ double wsum[4];
    if ((t & 63) == 0) wsum[t >> 6] = s;
    __syncthreads();
    if (t == 0) {
        double mean = (wsum[0] + wsum[1] + wsum[2] + wsum[3]) / (double)ZQ_SIZE;
        out[LOSS0_OFF] = (float)mean;
        out[LOSS1_OFF] = (float)mean;
    }
}

// ---------------------------------------------------------------------------
extern "C" void kernel_launch(void* const* d_in, const int* in_sizes, int n_in,
                              void* d_out, int out_size, void* d_ws, size_t ws_size,
                              hipStream_t stream) {
    const float* z_e = (const float*)d_in[0];
    const float* cb = (const float*)d_in[1];
    float* out = (float*)d_out;
    float* ws = (float*)d_ws;

    const ushort_t* eh = (const ushort_t*)ws;
    float* Bv = ws + WS_B;
    int* wsidx = (int*)(ws + WS_KIDX);
    float* part = ws + WS_PART;

    vq_prep<<<K, D, 0, stream>>>(cb, ws);
    vq_argmin2<<<NBLK_A, 256, 0, stream>>>(z_e, cb, eh, Bv, wsidx, out);
    vq_gather2<<<NBLK_G, 256, 0, stream>>>(z_e, cb, wsidx, part, out);
    vq_finish<<<1, 256, 0, stream>>>(part, out);
}

// Round 10
// 131.345 us; speedup vs baseline: 1.5429x; 1.2233x over previous
//
#include <hip/hip_runtime.h>

// VQ-VAE VectorQuantizer forward for MI355X (gfx950) — MFMA-filtered argmin.
// z_e: (64, 256, 32, 32) fp32; codebook: (512, 256) fp32.
// Outputs concatenated in d_out (float32):
//   [0, 16777216)        z_q_st  (== z_e + (z_q - z_e), fp32 elementwise)
//   [16777216]           commitment_loss
//   [16777217]           codebook_loss (same value)
//   [16777218, +65536)   indices (as float)
//
// Index semantics: bitwise emulation of numpy-fp32
//   d = sum(z**2,axis=1,keepdims=True) + sum(e**2,axis=1) - 2*matmul(z, e.T)
//   idx = argmin(d, axis=1)   (first occurrence on exact fp32 ties)
// Strategy: bf16(hi)-only MFMA computes approximate scores (|err| << EPS/2);
// per-row candidates within EPS of the approx min are re-scored with the
// bitwise-exact sequential fp32 FMA chain (ascending d) and reduced with
// (d asc, tie -> lower k). Overflowing rows fall back to exact scan of all K.
//
// ROUND-9 POST-MORTEM: per-lane VGPR loads of the codebook can never hold
// enough bytes in flight (Little's law: need ~22KB/CU in flight at L2
// latency; VGPR loads give ~3KB). The compiler also sinks source-level
// prefetch arrays (asked for 160 VGPR, got 76). This version stages the
// codebook via __builtin_amdgcn_global_load_lds (async DMA, no VGPR dest),
// 32KB step-tiles from a blocked layout written by vq_prep.

typedef __attribute__((ext_vector_type(8))) short short8v;
typedef __attribute__((ext_vector_type(4))) float float4v;
typedef unsigned short ushort_t;

#define GLOAD_LDS16(gsrc, ldst)                                                \
    __builtin_amdgcn_global_load_lds(                                          \
        (const __attribute__((address_space(1))) unsigned*)(gsrc),             \
        (__attribute__((address_space(3))) unsigned*)(ldst), 16, 0, 0)

namespace {
constexpr int K = 512;
constexpr int D = 256;
constexpr int HW = 1024;          // 32*32
constexpr int NROWS = 65536;      // 64*HW
constexpr int CHW = D * HW;       // 262144

constexpr int ZQ_SIZE = 64 * CHW; // 16777216
constexpr int LOSS0_OFF = ZQ_SIZE;
constexpr int LOSS1_OFF = ZQ_SIZE + 1;
constexpr int IDX_OFF = ZQ_SIZE + 2;

// workspace layout (float offsets)
// ehb: blocked bf16 codebook, 8 step-tiles of 32KB; tile s holds
// [kg 0..3][code 0..511][8 bf16] for d = s*32 + kg*8 + j.
constexpr int WS_EH_FLOATS = (K * D) / 2;  // 65536 floats = 256 KB
constexpr int WS_B = WS_EH_FLOATS;         // ||e_k||^2 (numpy pairwise), 512
constexpr int WS_KIDX = WS_B + K;          // best index per row (int), 65536
constexpr int WS_PART = WS_KIDX + NROWS;   // per-block loss partials, 2048

constexpr int NBLK_A = NROWS / 32;         // 2048 argmin blocks (32 rows)
constexpr int NBLK_G = 2048;               // 64 img x 4 hw-quarter x 8 c-group

constexpr float EPS_CAND = 3.0e-3f;        // candidate window (>> 2*max err)
constexpr int MAXC = 16;                   // candidate slots per row
}  // namespace

__device__ __forceinline__ ushort_t bf16_rne(float f) {
    unsigned u = __float_as_uint(f);
    u += 0x7fffu + ((u >> 16) & 1u);   // round-to-nearest-even (no NaN in data)
    return (ushort_t)(u >> 16);
}

// ---------------------------------------------------------------------------
// Kernel 1: blocked bf16 codebook + ||e_k||^2 in numpy pairwise order.
__global__ void vq_prep(const float* __restrict__ cb, float* __restrict__ ws) {
    const int k = blockIdx.x;
    const int t = threadIdx.x;  // 0..255 == d
    ushort_t* ehb = (ushort_t*)ws;
    {
        const int s = t >> 5;
        const int kg = (t >> 3) & 3;
        const int j = t & 7;
        ehb[(size_t)((s * 4 + kg) * 512 + k) * 8 + j] = bf16_rne(cb[k * D + t]);
    }
    __shared__ float r16[16];
    if (t < 16) {
#pragma clang fp contract(off)
        const float* x = cb + k * D + (t >> 3) * 128;
        const int j = t & 7;
        float v = x[j];
        float r = v * v;
        for (int i = 1; i < 16; ++i) {
            float w = x[8 * i + j];
            r += w * w;
        }
        r16[t] = r;
    }
    __syncthreads();
    if (t == 0) {
#pragma clang fp contract(off)
        float lo = ((r16[0] + r16[1]) + (r16[2] + r16[3])) +
                   ((r16[4] + r16[5]) + (r16[6] + r16[7]));
        float hi = ((r16[8] + r16[9]) + (r16[10] + r16[11])) +
                   ((r16[12] + r16[13]) + (r16[14] + r16[15]));
        ws[WS_B + k] = lo + hi;
    }
}

// ---------------------------------------------------------------------------
// Kernel 2: argmin. Per 32-row block (~57 KB LDS, 2 blocks/CU):
//   fused z pass: numpy-pairwise A chains + bf16-hi -> zh LDS;
//   K-loop: 8 steps of {DMA 32KB e-tile -> LDS, barrier, ds_read + MFMA,
//   barrier} — codebook bytes flow via async DMA, not VGPRs;
//   per-row approx min + candidate collection (<= min+EPS);
//   exact fp32-chain re-score of candidates; index write.
__global__ __launch_bounds__(256, 2) void vq_argmin4(
    const float* __restrict__ z_e, const float* __restrict__ cb,
    const ushort_t* __restrict__ ehb, const float* __restrict__ Bv,
    int* __restrict__ wsidx, float* __restrict__ out) {
    __shared__ __align__(16) ushort_t elds[4][512][8];  // 32 KB e step-tile
    __shared__ __align__(16) ushort_t zh[32][264];      // 16.9 KB bf16 hi
    __shared__ float lds_B[K];                          // 2 KB ||e_k||^2
    __shared__ float scr[32][17];                       // 2.2 KB pairwise acc
    __shared__ int cand[32][MAXC];                      // 2 KB candidates
    __shared__ float lds_A[32];
    __shared__ float wmin[4][32];
    __shared__ float rmin[32];
    __shared__ int cnt[32];

    const int t = threadIdx.x;
    const int row0 = blockIdx.x * 32;
    const int b = row0 >> 10;
    const int hw0 = row0 & 1023;
    const float* zbase = z_e + (size_t)b * CHW + hw0;

    // ---- B staging
    lds_B[t] = Bv[t];
    lds_B[t + 256] = Bv[t + 256];

    // ---- fused: A pairwise chains + bf16-hi conversion (single z read).
    {
        const int row = t & 31;
        const int q = t >> 5;
        const int half = q >> 2;
        const int j0 = (q & 3) * 2;
        const int cbase = half * 128;
        const float* zp = zbase + row;
        float za0[16], za1[16];
#pragma unroll
        for (int i = 0; i < 16; ++i) {
            const int c = cbase + 8 * i + j0;
            za0[i] = zp[(size_t)c * HW];
            za1[i] = zp[(size_t)(c + 1) * HW];
        }
        float r0, r1;
        {
#pragma clang fp contract(off)
            r0 = za0[0] * za0[0];
            r1 = za1[0] * za1[0];
#pragma unroll
            for (int i = 1; i < 16; ++i) {
                r0 += za0[i] * za0[i];
                r1 += za1[i] * za1[i];
            }
        }
#pragma unroll
        for (int i = 0; i < 16; ++i) {
            const int c = cbase + 8 * i + j0;
            *reinterpret_cast<unsigned*>(&zh[row][c]) =
                (unsigned)bf16_rne(za0[i]) | ((unsigned)bf16_rne(za1[i]) << 16);
        }
        scr[row][half * 8 + j0] = r0;
        scr[row][half * 8 + j0 + 1] = r1;
    }
    __syncthreads();
    if (t < 32) {
#pragma clang fp contract(off)
        const float* r = scr[t];
        float lo = ((r[0] + r[1]) + (r[2] + r[3])) + ((r[4] + r[5]) + (r[6] + r[7]));
        float hi = ((r[8] + r[9]) + (r[10] + r[11])) + ((r[12] + r[13]) + (r[14] + r[15]));
        lds_A[t] = lo + hi;
    }

    // ---- MFMA K-loop: wave w owns codes [w*128, w*128+128), all 32 rows.
    // A = E (codes = M) from the DMA-staged LDS tile, B = Z-hi (rows = N).
    // C frag (m89-verified): col = lane&15 = z-row; row = 4*(lane>>4)+reg = code.
    const int lane = t & 63;
    const int w = t >> 6;
    const int wc0 = w * 128;
    const int l15 = lane & 15;
    const int kg = lane >> 4;

    float4v acc[8][2];
#pragma unroll
    for (int c = 0; c < 8; ++c)
#pragma unroll
        for (int rt = 0; rt < 2; ++rt) acc[c][rt] = (float4v)0.f;

    const char* gtile = (const char*)ehb + (size_t)w * 8192 + (size_t)lane * 16;
    char* ltile = (char*)&elds[w][0][0];

    for (int s = 0; s < 8; ++s) {
        // stage step-tile s: wave w fills its kg=w region (8 x 1KB DMA)
        const char* gs = gtile + (size_t)s * 32768;
#pragma unroll
        for (int i = 0; i < 8; ++i) GLOAD_LDS16(gs + i * 1024, ltile + i * 1024);
        asm volatile("s_waitcnt vmcnt(0)" ::: "memory");
        __syncthreads();  // tile visible to all waves

        const int d0 = s * 32;
        const short8v bh0 = *reinterpret_cast<const short8v*>(&zh[l15][d0 + 8 * kg]);
        const short8v bh1 = *reinterpret_cast<const short8v*>(&zh[16 + l15][d0 + 8 * kg]);
#pragma unroll
        for (int c = 0; c < 8; ++c) {
            const short8v a =
                *reinterpret_cast<const short8v*>(&elds[kg][wc0 + c * 16 + l15][0]);
            acc[c][0] = __builtin_amdgcn_mfma_f32_16x16x32_bf16(a, bh0, acc[c][0], 0, 0, 0);
            acc[c][1] = __builtin_amdgcn_mfma_f32_16x16x32_bf16(a, bh1, acc[c][1], 0, 0, 0);
        }
        __syncthreads();  // compute done before next stage overwrites
    }

    // ---- approx scores + per-row min
    float lmin0 = 3.0e38f, lmin1 = 3.0e38f;
#pragma unroll
    for (int c = 0; c < 8; ++c)
#pragma unroll
        for (int rt = 0; rt < 2; ++rt)
#pragma unroll
            for (int r = 0; r < 4; ++r) {
                const int code = wc0 + 16 * c + 4 * kg + r;
                const int row = rt * 16 + l15;
                float s = (lds_A[row] + lds_B[code]) - 2.0f * acc[c][rt][r];
                acc[c][rt][r] = s;
                if (rt == 0) lmin0 = fminf(lmin0, s);
                else lmin1 = fminf(lmin1, s);
            }
    lmin0 = fminf(lmin0, __shfl_xor(lmin0, 16));
    lmin0 = fminf(lmin0, __shfl_xor(lmin0, 32));
    lmin1 = fminf(lmin1, __shfl_xor(lmin1, 16));
    lmin1 = fminf(lmin1, __shfl_xor(lmin1, 32));
    if (lane < 16) {
        wmin[w][l15] = lmin0;
        wmin[w][16 + l15] = lmin1;
    }
    __syncthreads();
    if (t < 32) {
        rmin[t] = fminf(fminf(wmin[0][t], wmin[1][t]), fminf(wmin[2][t], wmin[3][t]));
        cnt[t] = 0;
    }
    __syncthreads();

    // ---- candidate collection (any possible exact winner is within EPS)
#pragma unroll
    for (int c = 0; c < 8; ++c)
#pragma unroll
        for (int rt = 0; rt < 2; ++rt) {
            const int row = rt * 16 + l15;
            const float thr = rmin[row] + EPS_CAND;
#pragma unroll
            for (int r = 0; r < 4; ++r) {
                if (acc[c][rt][r] <= thr) {
                    const int code = wc0 + 16 * c + 4 * kg + r;
                    int slot = atomicAdd(&cnt[row], 1);
                    if (slot < MAXC) cand[row][slot] = code;
                }
            }
        }
    __syncthreads();

    // ---- exact pass: bitwise numpy-fp32 chain for rows with >=2 candidates.
    // zh buffer is dead now; alias reduction arrays onto it.
    float* ed = reinterpret_cast<float*>(&zh[0][0]);  // [8][32]
    int* ek = reinterpret_cast<int*>(ed + 256);       // [8][32]
    {
        const int row = t & 31;
        const int ct = t >> 5;  // 0..7 candidate-threads per row
        const float* zp = zbase + row;
        const int n = cnt[row];
        float bd = 3.0e38f;
        int bk = 0x7fffffff;
        if (n == 1) {
            if (ct == 0) {
                bd = -3.0e38f;
                bk = cand[row][0];
            }
        } else {
            const bool full = (n > MAXC);  // overflow: exact-scan all codes
            const int lim = full ? K : n;
            for (int s = ct; s < lim; s += 8) {
                const int k = full ? s : cand[row][s];
                const float* ep = cb + (size_t)k * D;
                float a = 0.f;
#pragma unroll 8
                for (int c = 0; c < D; ++c) a = fmaf(zp[(size_t)c * HW], ep[c], a);
                float dv;
                {
#pragma clang fp contract(off)
                    float t1 = lds_A[row] + lds_B[k];
                    dv = t1 - 2.0f * a;
                }
                if (dv < bd || (dv == bd && k < bk)) {
                    bd = dv;
                    bk = k;
                }
            }
        }
        ed[t] = bd;
        ek[t] = bk;
    }
    __syncthreads();
    if (t < 32) {
        float bd = ed[t];
        int bk = ek[t];
#pragma unroll
        for (int q = 1; q < 8; ++q) {
            float od = ed[q * 32 + t];
            int ok = ek[q * 32 + t];
            if (od < bd || (od == bd && ok < bk)) {
                bd = od;
                bk = ok;
            }
        }
        wsidx[row0 + t] = bk;
        out[IDX_OFF + row0 + t] = (float)bk;
    }
}

// ---------------------------------------------------------------------------
// Kernel 3: streaming gather / straight-through write / loss partials.
__global__ __launch_bounds__(256, 8) void vq_gather2(
    const float* __restrict__ z_e, const float* __restrict__ cb,
    const int* __restrict__ wsidx, float* __restrict__ part,
    float* __restrict__ out) {
    __shared__ float wpart[4];
    const int t = threadIdx.x;
    const int blk = blockIdx.x;
    const int cg = blk & 7;        // channel group (32 c)
    const int q = (blk >> 3) & 3;  // hw quarter (256 hw)
    const int b = blk >> 5;        // image
    const int lane = t & 63;
    const int csub = t >> 6;       // 0..3 (wave id)
    const int hw = q * 256 + lane * 4;

    const int4 kk = *reinterpret_cast<const int4*>(&wsidx[b * HW + hw]);
    const float* e0 = cb + (size_t)kk.x * D;
    const float* e1 = cb + (size_t)kk.y * D;
    const float* e2 = cb + (size_t)kk.z * D;
    const float* e3 = cb + (size_t)kk.w * D;
    const size_t zoff = (size_t)b * CHW + hw;

    float accum = 0.f;
#pragma unroll 2
    for (int i = 0; i < 8; ++i) {
        const int c = cg * 32 + csub * 8 + i;
        const size_t off = zoff + (size_t)c * HW;
        const float4 z4 = *reinterpret_cast<const float4*>(&z_e[off]);
        const float ex = e0[c], ey = e1[c], ez = e2[c], ew = e3[c];
        float4 o4;
        o4.x = z4.x + (ex - z4.x);
        o4.y = z4.y + (ey - z4.y);
        o4.z = z4.z + (ez - z4.z);
        o4.w = z4.w + (ew - z4.w);
        *reinterpret_cast<float4*>(&out[off]) = o4;
        accum = fmaf(z4.x - ex, z4.x - ex, accum);
        accum = fmaf(z4.y - ey, z4.y - ey, accum);
        accum = fmaf(z4.z - ez, z4.z - ez, accum);
        accum = fmaf(z4.w - ew, z4.w - ew, accum);
    }
#pragma unroll
    for (int m = 1; m < 64; m <<= 1) accum += __shfl_xor(accum, m);
    if (lane == 0) wpart[csub] = accum;
    __syncthreads();
    if (t == 0) part[blk] = (wpart[0] + wpart[1]) + (wpart[2] + wpart[3]);
}

// ---------------------------------------------------------------------------
// Kernel 4: final loss reduction (2048 partials, fp64, deterministic).
__global__ void vq_finish(const float* __restrict__ part, float* __restrict__ out) {
    const int t = threadIdx.x;  // 256 threads
    double s = 0.0;
#pragma unroll
    for (int i = 0; i < 8; ++i) s += (double)part[t + 256 * i];
#pragma unroll
    for (int m = 1; m < 64; m <<= 1) s += __shfl_xor(s, m);
    __shared__ double wsum[4];
    if ((t & 63) == 0) wsum[t >> 6] = s;
    __syncthreads();
    if (t == 0) {
        double mean = (wsum[0] + wsum[1] + wsum[2] + wsum[3]) / (double)ZQ_SIZE;
        out[LOSS0_OFF] = (float)mean;
        out[LOSS1_OFF] = (float)mean;
    }
}

// ---------------------------------------------------------------------------
extern "C" void kernel_launch(void* const* d_in, const int* in_sizes, int n_in,
                              void* d_out, int out_size, void* d_ws, size_t ws_size,
                              hipStream_t stream) {
    const float* z_e = (const float*)d_in[0];
    const float* cb = (const float*)d_in[1];
    float* out = (float*)d_out;
    float* ws = (float*)d_ws;

    const ushort_t* ehb = (const ushort_t*)ws;
    float* Bv = ws + WS_B;
    int* wsidx = (int*)(ws + WS_KIDX);
    float* part = ws + WS_PART;

    vq_prep<<<K, D, 0, stream>>>(cb, ws);
    vq_argmin4<<<NBLK_A, 256, 0, stream>>>(z_e, cb, ehb, Bv, wsidx, out);
    vq_gather2<<<NBLK_G, 256, 0, stream>>>(z_e, cb, wsidx, part, out);
    vq_finish<<<1, 256, 0, stream>>>(part, out);
}

// Round 11
// 121.221 us; speedup vs baseline: 1.6717x; 1.0835x over previous
//
#include <hip/hip_runtime.h>

// VQ-VAE VectorQuantizer forward for MI355X (gfx950) — MFMA-filtered argmin.
// z_e: (64, 256, 32, 32) fp32; codebook: (512, 256) fp32.
// Outputs concatenated in d_out (float32):
//   [0, 16777216)        z_q_st  (== z_e + (z_q - z_e), fp32 elementwise)
//   [16777216]           commitment_loss
//   [16777217]           codebook_loss (same value)
//   [16777218, +65536)   indices (as float)
//
// Index semantics: bitwise emulation of numpy-fp32
//   d = sum(z**2,axis=1,keepdims=True) + sum(e**2,axis=1) - 2*matmul(z, e.T)
//   idx = argmin(d, axis=1)   (first occurrence on exact fp32 ties)
// Strategy: bf16(hi)-only MFMA computes approximate scores (|err| << EPS/2);
// per-row candidates within EPS of the approx min are re-scored with the
// bitwise-exact sequential fp32 FMA chain (ascending d) and reduced with
// (d asc, tie -> lower k). Overflowing rows fall back to exact scan of all K.
//
// ROUND-10 POST-MORTEM: three serial latency phases per block (strided z
// global loads with compiler-sunk prefetch; exact-pass chains re-reading z
// from global; e-tile DMA convoy). Root cause: z touched 3x via global.
// THIS VERSION: z staged ONCE to LDS (zf, fp32, global_load_lds) and all
// consumers (A-norm, bf16 b-frags, exact chains) read LDS. zh removed.

typedef __attribute__((ext_vector_type(8))) short short8v;
typedef __attribute__((ext_vector_type(4))) float float4v;
typedef unsigned short ushort_t;

#define GLOAD_LDS16(gsrc, ldst)                                                \
    __builtin_amdgcn_global_load_lds(                                          \
        (const __attribute__((address_space(1))) unsigned*)(gsrc),             \
        (__attribute__((address_space(3))) unsigned*)(ldst), 16, 0, 0)

namespace {
constexpr int K = 512;
constexpr int D = 256;
constexpr int HW = 1024;          // 32*32
constexpr int NROWS = 65536;      // 64*HW
constexpr int CHW = D * HW;       // 262144

constexpr int ZQ_SIZE = 64 * CHW; // 16777216
constexpr int LOSS0_OFF = ZQ_SIZE;
constexpr int LOSS1_OFF = ZQ_SIZE + 1;
constexpr int IDX_OFF = ZQ_SIZE + 2;

// workspace layout (float offsets)
// ehb: blocked bf16 codebook, 8 step-tiles of 32KB; tile s holds
// [kg 0..3][code 0..511][8 bf16] for d = s*32 + kg*8 + j.
constexpr int WS_EH_FLOATS = (K * D) / 2;  // 65536 floats = 256 KB
constexpr int WS_B = WS_EH_FLOATS;         // ||e_k||^2 (numpy pairwise), 512
constexpr int WS_KIDX = WS_B + K;          // best index per row (int), 65536
constexpr int WS_PART = WS_KIDX + NROWS;   // per-block loss partials, 2048

constexpr int NBLK_A = NROWS / 32;         // 2048 argmin blocks (32 rows)
constexpr int NBLK_G = 2048;               // 64 img x 4 hw-quarter x 8 c-group

constexpr float EPS_CAND = 3.0e-3f;        // candidate window (>> 2*max err)
constexpr int MAXC = 16;                   // candidate slots per row
}  // namespace

__device__ __forceinline__ ushort_t bf16_rne(float f) {
    unsigned u = __float_as_uint(f);
    u += 0x7fffu + ((u >> 16) & 1u);   // round-to-nearest-even (no NaN in data)
    return (ushort_t)(u >> 16);
}

// ---------------------------------------------------------------------------
// Kernel 1: blocked bf16 codebook + ||e_k||^2 in numpy pairwise order.
__global__ void vq_prep(const float* __restrict__ cb, float* __restrict__ ws) {
    const int k = blockIdx.x;
    const int t = threadIdx.x;  // 0..255 == d
    ushort_t* ehb = (ushort_t*)ws;
    {
        const int s = t >> 5;
        const int kg = (t >> 3) & 3;
        const int j = t & 7;
        ehb[(size_t)((s * 4 + kg) * 512 + k) * 8 + j] = bf16_rne(cb[k * D + t]);
    }
    __shared__ float r16[16];
    if (t < 16) {
#pragma clang fp contract(off)
        const float* x = cb + k * D + (t >> 3) * 128;
        const int j = t & 7;
        float v = x[j];
        float r = v * v;
        for (int i = 1; i < 16; ++i) {
            float w = x[8 * i + j];
            r += w * w;
        }
        r16[t] = r;
    }
    __syncthreads();
    if (t == 0) {
#pragma clang fp contract(off)
        float lo = ((r16[0] + r16[1]) + (r16[2] + r16[3])) +
                   ((r16[4] + r16[5]) + (r16[6] + r16[7]));
        float hi = ((r16[8] + r16[9]) + (r16[10] + r16[11])) +
                   ((r16[12] + r16[13]) + (r16[14] + r16[15]));
        ws[WS_B + k] = lo + hi;
    }
}

// ---------------------------------------------------------------------------
// Kernel 2: argmin. Per 32-row block (~71 KB LDS, 2 blocks/CU):
//   z DMA'd ONCE to zf[256][32] fp32 (one vmcnt drain);
//   A pairwise chains from LDS; per-step bf16 b-frags built from LDS
//   (overlapping the e-tile DMA); MFMA; candidates; exact fp32 chains
//   from LDS; index write.
__global__ __launch_bounds__(256, 2) void vq_argmin5(
    const float* __restrict__ z_e, const float* __restrict__ cb,
    const ushort_t* __restrict__ ehb, const float* __restrict__ Bv,
    int* __restrict__ wsidx, float* __restrict__ out) {
    __shared__ __align__(16) float zf[256][32];         // 32 KB z fp32 [c][row]
    __shared__ __align__(16) ushort_t elds[4][512][8];  // 32 KB e step-tile
    __shared__ float lds_B[K];                          // 2 KB ||e_k||^2
    __shared__ float scr[32][17];                       // 2.2 KB pairwise acc
    __shared__ int cand[32][MAXC];                      // 2 KB candidates
    __shared__ float lds_A[32];
    __shared__ float wmin[4][32];
    __shared__ float rmin[32];
    __shared__ int cnt[32];

    const int t = threadIdx.x;
    const int lane = t & 63;
    const int w = t >> 6;
    const int row0 = blockIdx.x * 32;
    const int b = row0 >> 10;
    const int hw0 = row0 & 1023;
    const float* zbase = z_e + (size_t)b * CHW + hw0;

    // ---- stage z -> zf via async DMA: wave w covers channels [w*64, w*64+64).
    // Issue i: 1KB = 8 channels; lane l: channel +=(l>>3), bytes (l&7)*16.
    {
        const char* zg = (const char*)zbase;
        char* zl = (char*)&zf[0][0];
#pragma unroll
        for (int i = 0; i < 8; ++i) {
            const int cc = (w * 8 + i) * 8 + (lane >> 3);
            GLOAD_LDS16(zg + (size_t)cc * 4096 + (lane & 7) * 16,
                        zl + (size_t)(w * 8 + i) * 1024);
        }
    }
    // ---- B staging (normal loads; drained by the same vmcnt)
    lds_B[t] = Bv[t];
    lds_B[t + 256] = Bv[t + 256];
    asm volatile("s_waitcnt vmcnt(0)" ::: "memory");
    __syncthreads();  // zf complete

    // ---- A = ||z_row||^2, exact numpy pairwise order, from LDS.
    {
        const int row = t & 31;
        const int q = t >> 5;
        const int half = q >> 2;
        const int j0 = (q & 3) * 2;
        const int cbase = half * 128;
        float r0, r1;
        {
#pragma clang fp contract(off)
            float w0 = zf[cbase + j0][row];
            float w1 = zf[cbase + j0 + 1][row];
            r0 = w0 * w0;
            r1 = w1 * w1;
#pragma unroll
            for (int i = 1; i < 16; ++i) {
                float u0 = zf[cbase + 8 * i + j0][row];
                float u1 = zf[cbase + 8 * i + j0 + 1][row];
                r0 += u0 * u0;
                r1 += u1 * u1;
            }
        }
        scr[row][half * 8 + j0] = r0;
        scr[row][half * 8 + j0 + 1] = r1;
    }
    __syncthreads();
    if (t < 32) {
#pragma clang fp contract(off)
        const float* r = scr[t];
        float lo = ((r[0] + r[1]) + (r[2] + r[3])) + ((r[4] + r[5]) + (r[6] + r[7]));
        float hi = ((r[8] + r[9]) + (r[10] + r[11])) + ((r[12] + r[13]) + (r[14] + r[15]));
        lds_A[t] = lo + hi;
    }

    // ---- MFMA K-loop: wave w owns codes [w*128, w*128+128), all 32 rows.
    // A = E (codes = M) from DMA-staged elds, B = Z-hi built from zf.
    // C frag (m89-verified): col = lane&15 = z-row; row = 4*(lane>>4)+reg = code.
    const int wc0 = w * 128;
    const int l15 = lane & 15;
    const int kg = lane >> 4;

    float4v acc[8][2];
#pragma unroll
    for (int c = 0; c < 8; ++c)
#pragma unroll
        for (int rt = 0; rt < 2; ++rt) acc[c][rt] = (float4v)0.f;

    const char* gtile = (const char*)ehb + (size_t)w * 8192 + (size_t)lane * 16;
    char* ltile = (char*)&elds[w][0][0];

    for (int s = 0; s < 8; ++s) {
        // stage e step-tile s (8 x 1KB DMA per wave)
        const char* gs = gtile + (size_t)s * 32768;
#pragma unroll
        for (int i = 0; i < 8; ++i) GLOAD_LDS16(gs + i * 1024, ltile + i * 1024);

        // build b-frags from zf while the DMA is in flight
        const int d0 = s * 32;
        short8v bh0, bh1;
#pragma unroll
        for (int j = 0; j < 8; ++j) {
            bh0[j] = (short)bf16_rne(zf[d0 + 8 * kg + j][l15]);
            bh1[j] = (short)bf16_rne(zf[d0 + 8 * kg + j][16 + l15]);
        }

        asm volatile("s_waitcnt vmcnt(0)" ::: "memory");
        __syncthreads();  // tile visible to all waves

#pragma unroll
        for (int c = 0; c < 8; ++c) {
            const short8v a =
                *reinterpret_cast<const short8v*>(&elds[kg][wc0 + c * 16 + l15][0]);
            acc[c][0] = __builtin_amdgcn_mfma_f32_16x16x32_bf16(a, bh0, acc[c][0], 0, 0, 0);
            acc[c][1] = __builtin_amdgcn_mfma_f32_16x16x32_bf16(a, bh1, acc[c][1], 0, 0, 0);
        }
        __syncthreads();  // compute done before next stage overwrites
    }

    // ---- approx scores + per-row min
    float lmin0 = 3.0e38f, lmin1 = 3.0e38f;
#pragma unroll
    for (int c = 0; c < 8; ++c)
#pragma unroll
        for (int rt = 0; rt < 2; ++rt)
#pragma unroll
            for (int r = 0; r < 4; ++r) {
                const int code = wc0 + 16 * c + 4 * kg + r;
                const int row = rt * 16 + l15;
                float s = (lds_A[row] + lds_B[code]) - 2.0f * acc[c][rt][r];
                acc[c][rt][r] = s;
                if (rt == 0) lmin0 = fminf(lmin0, s);
                else lmin1 = fminf(lmin1, s);
            }
    lmin0 = fminf(lmin0, __shfl_xor(lmin0, 16));
    lmin0 = fminf(lmin0, __shfl_xor(lmin0, 32));
    lmin1 = fminf(lmin1, __shfl_xor(lmin1, 16));
    lmin1 = fminf(lmin1, __shfl_xor(lmin1, 32));
    if (lane < 16) {
        wmin[w][l15] = lmin0;
        wmin[w][16 + l15] = lmin1;
    }
    __syncthreads();
    if (t < 32) {
        rmin[t] = fminf(fminf(wmin[0][t], wmin[1][t]), fminf(wmin[2][t], wmin[3][t]));
        cnt[t] = 0;
    }
    __syncthreads();

    // ---- candidate collection (any possible exact winner is within EPS)
#pragma unroll
    for (int c = 0; c < 8; ++c)
#pragma unroll
        for (int rt = 0; rt < 2; ++rt) {
            const int row = rt * 16 + l15;
            const float thr = rmin[row] + EPS_CAND;
#pragma unroll
            for (int r = 0; r < 4; ++r) {
                if (acc[c][rt][r] <= thr) {
                    const int code = wc0 + 16 * c + 4 * kg + r;
                    int slot = atomicAdd(&cnt[row], 1);
                    if (slot < MAXC) cand[row][slot] = code;
                }
            }
        }
    __syncthreads();

    // ---- exact pass: bitwise numpy-fp32 chain for rows with >=2 candidates.
    // z from LDS (zf). elds is dead now; alias reduction arrays onto it.
    float* ed = reinterpret_cast<float*>(&elds[0][0][0]);  // [8][32]
    int* ek = reinterpret_cast<int*>(ed + 256);            // [8][32]
    {
        const int row = t & 31;
        const int ct = t >> 5;  // 0..7 candidate-threads per row
        const int n = cnt[row];
        float bd = 3.0e38f;
        int bk = 0x7fffffff;
        if (n == 1) {
            if (ct == 0) {
                bd = -3.0e38f;
                bk = cand[row][0];
            }
        } else {
            const bool full = (n > MAXC);  // overflow: exact-scan all codes
            const int lim = full ? K : n;
            for (int s = ct; s < lim; s += 8) {
                const int k = full ? s : cand[row][s];
                const float* ep = cb + (size_t)k * D;
                float a = 0.f;
#pragma unroll 8
                for (int c = 0; c < D; ++c) a = fmaf(zf[c][row], ep[c], a);
                float dv;
                {
#pragma clang fp contract(off)
                    float t1 = lds_A[row] + lds_B[k];
                    dv = t1 - 2.0f * a;
                }
                if (dv < bd || (dv == bd && k < bk)) {
                    bd = dv;
                    bk = k;
                }
            }
        }
        ed[t] = bd;
        ek[t] = bk;
    }
    __syncthreads();
    if (t < 32) {
        float bd = ed[t];
        int bk = ek[t];
#pragma unroll
        for (int q = 1; q < 8; ++q) {
            float od = ed[q * 32 + t];
            int ok = ek[q * 32 + t];
            if (od < bd || (od == bd && ok < bk)) {
                bd = od;
                bk = ok;
            }
        }
        wsidx[row0 + t] = bk;
        out[IDX_OFF + row0 + t] = (float)bk;
    }
}

// ---------------------------------------------------------------------------
// Kernel 3: streaming gather / straight-through write / loss partials.
__global__ __launch_bounds__(256, 8) void vq_gather2(
    const float* __restrict__ z_e, const float* __restrict__ cb,
    const int* __restrict__ wsidx, float* __restrict__ part,
    float* __restrict__ out) {
    __shared__ float wpart[4];
    const int t = threadIdx.x;
    const int blk = blockIdx.x;
    const int cg = blk & 7;        // channel group (32 c)
    const int q = (blk >> 3) & 3;  // hw quarter (256 hw)
    const int b = blk >> 5;        // image
    const int lane = t & 63;
    const int csub = t >> 6;       // 0..3 (wave id)
    const int hw = q * 256 + lane * 4;

    const int4 kk = *reinterpret_cast<const int4*>(&wsidx[b * HW + hw]);
    const float* e0 = cb + (size_t)kk.x * D;
    const float* e1 = cb + (size_t)kk.y * D;
    const float* e2 = cb + (size_t)kk.z * D;
    const float* e3 = cb + (size_t)kk.w * D;
    const size_t zoff = (size_t)b * CHW + hw;

    float accum = 0.f;
#pragma unroll 2
    for (int i = 0; i < 8; ++i) {
        const int c = cg * 32 + csub * 8 + i;
        const size_t off = zoff + (size_t)c * HW;
        const float4 z4 = *reinterpret_cast<const float4*>(&z_e[off]);
        const float ex = e0[c], ey = e1[c], ez = e2[c], ew = e3[c];
        float4 o4;
        o4.x = z4.x + (ex - z4.x);
        o4.y = z4.y + (ey - z4.y);
        o4.z = z4.z + (ez - z4.z);
        o4.w = z4.w + (ew - z4.w);
        *reinterpret_cast<float4*>(&out[off]) = o4;
        accum = fmaf(z4.x - ex, z4.x - ex, accum);
        accum = fmaf(z4.y - ey, z4.y - ey, accum);
        accum = fmaf(z4.z - ez, z4.z - ez, accum);
        accum = fmaf(z4.w - ew, z4.w - ew, accum);
    }
#pragma unroll
    for (int m = 1; m < 64; m <<= 1) accum += __shfl_xor(accum, m);
    if (lane == 0) wpart[csub] = accum;
    __syncthreads();
    if (t == 0) part[blk] = (wpart[0] + wpart[1]) + (wpart[2] + wpart[3]);
}

// ---------------------------------------------------------------------------
// Kernel 4: final loss reduction (2048 partials, fp64, deterministic).
__global__ void vq_finish(const float* __restrict__ part, float* __restrict__ out) {
    const int t = threadIdx.x;  // 256 threads
    double s = 0.0;
#pragma unroll
    for (int i = 0; i < 8; ++i) s += (double)part[t + 256 * i];
#pragma unroll
    for (int m = 1; m < 64; m <<= 1) s += __shfl_xor(s, m);
    __shared__ double wsum[4];
    if ((t & 63) == 0) wsum[t >> 6] = s;
    __syncthreads();
    if (t == 0) {
        double mean = (wsum[0] + wsum[1] + wsum[2] + wsum[3]) / (double)ZQ_SIZE;
        out[LOSS0_OFF] = (float)mean;
        out[LOSS1_OFF] = (float)mean;
    }
}

// ---------------------------------------------------------------------------
extern "C" void kernel_launch(void* const* d_in, const int* in_sizes, int n_in,
                              void* d_out, int out_size, void* d_ws, size_t ws_size,
                              hipStream_t stream) {
    const float* z_e = (const float*)d_in[0];
    const float* cb = (const float*)d_in[1];
    float* out = (float*)d_out;
    float* ws = (float*)d_ws;

    const ushort_t* ehb = (const ushort_t*)ws;
    float* Bv = ws + WS_B;
    int* wsidx = (int*)(ws + WS_KIDX);
    float* part = ws + WS_PART;

    vq_prep<<<K, D, 0, stream>>>(cb, ws);
    vq_argmin5<<<NBLK_A, 256, 0, stream>>>(z_e, cb, ehb, Bv, wsidx, out);
    vq_gather2<<<NBLK_G, 256, 0, stream>>>(z_e, cb, wsidx, part, out);
    vq_finish<<<1, 256, 0, stream>>>(part, out);
}